// Round 2
// baseline (153.799 us; speedup 1.0000x reference)
//
#include <hip/hip_runtime.h>
#include <hip/hip_bf16.h>

#define NB 4
#define NQ 512
#define NK 2048
#define ND 256
#define NH 64
#define QT 8                      // queries per block in kernel B

#define SCALE_C 2.8853900817779268f   // 2*log2(e): exp2(C*(q+k)) = e^{2(q+k)}
#define L2E     1.4426950408889634f

__device__ __forceinline__ float wred_max(float v) {
#pragma unroll
    for (int off = 32; off; off >>= 1) v = fmaxf(v, __shfl_xor(v, off, 64));
    return v;
}
__device__ __forceinline__ float wred_sum(float v) {
#pragma unroll
    for (int off = 32; off; off >>= 1) v += __shfl_xor(v, off, 64);
    return v;
}

// ---------- kernel A: projections, pre-scaled by 2*log2(e) ----------
// rows 0..NB*NQ-1 -> qp (queries @ Wq), rows NB*NQ.. -> kp (keys @ Wk)
__global__ __launch_bounds__(256) void proj_kernel(
    const float* __restrict__ queries, const float* __restrict__ keys,
    const float* __restrict__ Wq, const float* __restrict__ Wk,
    float* __restrict__ qp, float* __restrict__ kp)
{
    __shared__ __align__(16) float in_lds[16][256];
    const int t = threadIdx.x;
    const int row0 = blockIdx.x * 16;
    const bool isQ = row0 < NB * NQ;
    const float* src = isQ ? (queries + (size_t)row0 * ND)
                           : (keys + (size_t)(row0 - NB * NQ) * ND);
    const float* W = isQ ? Wq : Wk;
    float* dst = isQ ? (qp + (size_t)row0 * NH)
                     : (kp + (size_t)(row0 - NB * NQ) * NH);

    const float4* src4 = (const float4*)src;
#pragma unroll
    for (int i = 0; i < 4; ++i) {
        int f4 = t + 256 * i;                 // 0..1023
        ((float4*)&in_lds[0][0])[f4] = src4[f4];
    }
    __syncthreads();

    const int w = t >> 6, h = t & 63;
    const int r0 = w * 4;                     // each wave: 4 rows, lane = h
    float a0 = 0.f, a1 = 0.f, a2 = 0.f, a3 = 0.f;
#pragma unroll 4
    for (int d4 = 0; d4 < 64; ++d4) {
        float4 x0 = ((const float4*)in_lds[r0 + 0])[d4];   // broadcast reads
        float4 x1 = ((const float4*)in_lds[r0 + 1])[d4];
        float4 x2 = ((const float4*)in_lds[r0 + 2])[d4];
        float4 x3 = ((const float4*)in_lds[r0 + 3])[d4];
        const float* Wp = W + (size_t)(d4 * 4) * NH + h;   // coalesced across lanes
        float w0 = Wp[0], w1 = Wp[NH], w2 = Wp[2 * NH], w3 = Wp[3 * NH];
        a0 = fmaf(x0.x, w0, fmaf(x0.y, w1, fmaf(x0.z, w2, fmaf(x0.w, w3, a0))));
        a1 = fmaf(x1.x, w0, fmaf(x1.y, w1, fmaf(x1.z, w2, fmaf(x1.w, w3, a1))));
        a2 = fmaf(x2.x, w0, fmaf(x2.y, w1, fmaf(x2.z, w2, fmaf(x2.w, w3, a2))));
        a3 = fmaf(x3.x, w0, fmaf(x3.y, w1, fmaf(x3.z, w2, fmaf(x3.w, w3, a3))));
    }
    dst[(size_t)(r0 + 0) * NH + h] = a0 * SCALE_C;
    dst[(size_t)(r0 + 1) * NH + h] = a1 * SCALE_C;
    dst[(size_t)(r0 + 2) * NH + h] = a2 * SCALE_C;
    dst[(size_t)(r0 + 3) * NH + h] = a3 * SCALE_C;
}

// ---------- kernel B: scores + masked softmax + PV ----------
// grid = NB * (NQ/QT) = 256 blocks, 512 threads (8 waves)
__global__ __launch_bounds__(512) void attn_kernel(
    const float* __restrict__ values, const int* __restrict__ valid_lens,
    const float* __restrict__ wv,
    const float* __restrict__ qp, const float* __restrict__ kp,
    float* __restrict__ out)
{
    __shared__ __align__(16) float qp_l[QT][NH];          // 2 KB
    __shared__ __align__(16) float wv2_l[NH];             // -2*wv
    __shared__ float sumwv_l;
    __shared__ __align__(16) float p_l[QT][NK];           // 64 KB (f32 scores -> e-values)
    __shared__ float red_l[QT][8];

    const int t = threadIdx.x;
    const int b = blockIdx.x >> 6;            // 64 q-tiles per batch
    const int q0 = (blockIdx.x & 63) * QT;

    // stage qp rows (already scaled)
    if (t < 128) {
        int q = t >> 4, h4 = t & 15;
        ((float4*)qp_l[q])[h4] =
            ((const float4*)(qp + (size_t)(b * NQ + q0 + q) * NH))[h4];
    }
    if (t < 64) {
        float wvv = wv[t];
        wv2_l[t] = -2.0f * wvv;
        float s = wred_sum(wvv);
        if (t == 0) sumwv_l = s;
    }
    int vl = valid_lens[b];                   // int32 per harness convention
    const int kv = vl < 0 ? 0 : (vl > NK ? NK : vl);
    __syncthreads();

    const float sumwv = sumwv_l;

    // ---- phase 1: raw scores -> p_l (f32) ----
    // s(q,k) = sum_h wv[h]*tanh(qh+kh) = sumwv + sum_h wv2[h] / (1 + e^{2(qh+kh)})
#pragma unroll 1
    for (int chunk = 0; chunk < NK / 512; ++chunk) {
        int k = chunk * 512 + t;
        if (kv == 0) {
#pragma unroll
            for (int q = 0; q < QT; ++q) p_l[q][k] = 1.0f;   // uniform e-values
        } else if (k < kv) {
            float s[QT];
#pragma unroll
            for (int q = 0; q < QT; ++q) s[q] = 0.f;
            const float4* kr = (const float4*)(kp + (size_t)(b * NK + k) * NH);
#pragma unroll 2
            for (int h4 = 0; h4 < 16; ++h4) {
                float4 kh = kr[h4];
                float4 w4 = ((const float4*)wv2_l)[h4];
#pragma unroll
                for (int q = 0; q < QT; ++q) {
                    float4 qh = ((const float4*)qp_l[q])[h4];   // broadcast
                    float r0 = __builtin_amdgcn_rcpf(__builtin_amdgcn_exp2f(qh.x + kh.x) + 1.0f);
                    float r1 = __builtin_amdgcn_rcpf(__builtin_amdgcn_exp2f(qh.y + kh.y) + 1.0f);
                    float r2 = __builtin_amdgcn_rcpf(__builtin_amdgcn_exp2f(qh.z + kh.z) + 1.0f);
                    float r3 = __builtin_amdgcn_rcpf(__builtin_amdgcn_exp2f(qh.w + kh.w) + 1.0f);
                    s[q] = fmaf(w4.x, r0, s[q]);
                    s[q] = fmaf(w4.y, r1, s[q]);
                    s[q] = fmaf(w4.z, r2, s[q]);
                    s[q] = fmaf(w4.w, r3, s[q]);
                }
            }
#pragma unroll
            for (int q = 0; q < QT; ++q) p_l[q][k] = s[q] + sumwv;
        } else {
#pragma unroll
            for (int q = 0; q < QT; ++q) p_l[q][k] = -3.0e38f;  // masked
        }
    }
    __syncthreads();

    // ---- phase 2: softmax stats (skip if kv==0: weights already uniform 1.0) ----
    float mq[QT];
    if (kv > 0) {
        const int wid = t >> 6;
        // pass A: max
#pragma unroll
        for (int q = 0; q < QT; ++q) {
            float4 v = *(const float4*)&p_l[q][t * 4];
            float mm = fmaxf(fmaxf(v.x, v.y), fmaxf(v.z, v.w));
            mm = wred_max(mm);
            if ((t & 63) == 0) red_l[q][wid] = mm;
        }
        __syncthreads();
#pragma unroll
        for (int q = 0; q < QT; ++q) {
            float m = red_l[q][0];
#pragma unroll
            for (int i = 1; i < 8; ++i) m = fmaxf(m, red_l[q][i]);
            mq[q] = m;
        }
        __syncthreads();
        // pass B: e = exp(s-m) (unnormalized), write back, accumulate sums
#pragma unroll
        for (int q = 0; q < QT; ++q) {
            float4 v = *(const float4*)&p_l[q][t * 4];
            float e0 = __builtin_amdgcn_exp2f((v.x - mq[q]) * L2E);
            float e1 = __builtin_amdgcn_exp2f((v.y - mq[q]) * L2E);
            float e2 = __builtin_amdgcn_exp2f((v.z - mq[q]) * L2E);
            float e3 = __builtin_amdgcn_exp2f((v.w - mq[q]) * L2E);
            *(float4*)&p_l[q][t * 4] = make_float4(e0, e1, e2, e3);
            float ssum = wred_sum((e0 + e1) + (e2 + e3));
            if ((t & 63) == 0) red_l[q][wid] = ssum;
        }
    }
    __syncthreads();

    // ---- phase 3: PV. wave w owns q=w, lanes cover d ----
    const int q = t >> 6;
    const int dl = (t & 63) * 4;              // 64 lanes x 4 = 256 d
    float4 acc = make_float4(0.f, 0.f, 0.f, 0.f);
    float linv;
    if (kv == 0) {
        linv = 1.0f / (float)NK;
    } else {
        float l = red_l[q][0];
#pragma unroll
        for (int i = 1; i < 8; ++i) l += red_l[q][i];
        linv = 1.0f / l;
    }
    const int kend = (kv == 0) ? NK : ((kv + 7) & ~7);
    const float* Vb = values + (size_t)b * NK * ND;
#pragma unroll 1
    for (int kk = 0; kk < kend; kk += 8) {
        float4 pa = *(const float4*)&p_l[q][kk];          // wave-uniform broadcast
        float4 pb = *(const float4*)&p_l[q][kk + 4];
        float pr[8] = {pa.x, pa.y, pa.z, pa.w, pb.x, pb.y, pb.z, pb.w};
        const float* vr = Vb + (size_t)kk * ND + dl;
#pragma unroll
        for (int j = 0; j < 8; ++j) {
            float4 v = *(const float4*)(vr + (size_t)j * ND);  // coalesced 1KB/row
            acc.x = fmaf(pr[j], v.x, acc.x);
            acc.y = fmaf(pr[j], v.y, acc.y);
            acc.z = fmaf(pr[j], v.z, acc.z);
            acc.w = fmaf(pr[j], v.w, acc.w);
        }
    }
    float* orow = out + (size_t)(b * NQ + q0 + q) * ND + dl;
    float4 o = make_float4(acc.x * linv, acc.y * linv, acc.z * linv, acc.w * linv);
    *(float4*)orow = o;
}

extern "C" void kernel_launch(void* const* d_in, const int* in_sizes, int n_in,
                              void* d_out, int out_size, void* d_ws, size_t ws_size,
                              hipStream_t stream) {
    const float* queries   = (const float*)d_in[0];
    const float* keys      = (const float*)d_in[1];
    const float* values    = (const float*)d_in[2];
    const int* valid_lens  = (const int*)d_in[3];      // harness passes integers as int32
    const float* Wq        = (const float*)d_in[4];
    const float* Wk        = (const float*)d_in[5];
    const float* wv        = (const float*)d_in[6];
    float* out = (float*)d_out;

    float* qp = (float*)d_ws;                       // NB*NQ*NH f32
    float* kp = qp + (size_t)NB * NQ * NH;          // NB*NK*NH f32

    proj_kernel<<<(NB * NQ + NB * NK) / 16, 256, 0, stream>>>(queries, keys, Wq, Wk, qp, kp);
    attn_kernel<<<NB * (NQ / QT), 512, 0, stream>>>(values, valid_lens, wv, qp, kp, out);
}